// Round 4
// baseline (290.263 us; speedup 1.0000x reference)
//
#include <hip/hip_runtime.h>

#define FDIM 512

__device__ __forceinline__ float4 ld4(const float* p) { return *(const float4*)p; }

// Fused per-batch kernel. One block = one batch (256 blocks on 256 CUs,
// 16 waves each). Wave w owns rows [32w, 32w+32), processed in 8 groups of
// 4 rows with a 2-buffer software pipeline (8 float4 loads issued one full
// group ahead). No barriers anywhere in the streaming loops.
__global__ __launch_bounds__(1024)
void rvsoftmax_deep(const float* __restrict__ mu,
                    const float* __restrict__ Sigma,
                    float* __restrict__ p_out,
                    float* __restrict__ S_out) {
    const int b = blockIdx.x;
    const int t = threadIdx.x;
    const int w = t >> 6;   // wave 0..15
    const int l = t & 63;   // lane 0..63

    __shared__ __align__(16) float p_lds[FDIM];
    __shared__ __align__(16) float r_lds[FDIM];
    __shared__ __align__(16) float c_lds[FDIM];
    __shared__ __align__(16) float cst[16][FDIM];   // 32 KB c-partial stage
    __shared__ float red[16];
    __shared__ float sc[2];

    const float* Sb = Sigma + (size_t)b * FDIM * FDIM;
    float* Ob       = S_out + (size_t)b * FDIM * FDIM;
    const int i0 = w * 32;
    const float* base = Sb + (size_t)i0 * FDIM + 4 * l;

    float4 A[8], B[8];

#define LOADG(arr, g) do {                                                  \
    const float* gp_ = base + (size_t)(g) * 4 * FDIM;                       \
    _Pragma("unroll")                                                       \
    for (int q_ = 0; q_ < 4; ++q_) {                                        \
        arr[2*q_]   = ld4(gp_ + q_ * FDIM);                                 \
        arr[2*q_+1] = ld4(gp_ + q_ * FDIM + 256);                           \
    } } while (0)

    // Issue two groups' loads immediately — they fly during the softmax.
    LOADG(A, 0);
    LOADG(B, 1);

    // ---------------- softmax over mu[b,:] ----------------
    float x = (t < FDIM) ? mu[(size_t)b * FDIM + t] : -__builtin_inff();
    float m = x;
    #pragma unroll
    for (int off = 32; off >= 1; off >>= 1) m = fmaxf(m, __shfl_xor(m, off));
    if (l == 0) red[w] = m;
    __syncthreads();
    if (t == 0) {
        float mm = red[0];
        for (int j = 1; j < 16; ++j) mm = fmaxf(mm, red[j]);
        sc[0] = mm;
    }
    __syncthreads();
    const float mx = sc[0];
    float e = (t < FDIM) ? __expf(x - mx) : 0.f;
    float ssum = e;
    #pragma unroll
    for (int off = 32; off >= 1; off >>= 1) ssum += __shfl_xor(ssum, off);
    if (l == 0) red[w] = ssum;
    __syncthreads();
    if (t == 0) {
        float tt = 0.f;
        for (int j = 0; j < 16; ++j) tt += red[j];
        sc[0] = tt;
    }
    __syncthreads();
    const float inv = 1.0f / sc[0];
    if (t < FDIM) {
        float pv = e * inv;
        p_lds[t] = pv;
        p_out[(size_t)b * FDIM + t] = pv;
    }
    __syncthreads();

    const float4 p0 = ld4(&p_lds[4 * l]);
    const float4 p1 = ld4(&p_lds[256 + 4 * l]);

    // ---------------- Phase 1: r_i and c-partials, barrier-free ---------
    float4 c0 = make_float4(0.f, 0.f, 0.f, 0.f);
    float4 c1 = make_float4(0.f, 0.f, 0.f, 0.f);

#define COMP1(arr, g) do {                                                  \
    _Pragma("unroll")                                                       \
    for (int q_ = 0; q_ < 4; ++q_) {                                        \
        const int i_ = i0 + (g) * 4 + q_;                                   \
        const float4 x0 = arr[2*q_], x1 = arr[2*q_+1];                      \
        float dot = x0.x*p0.x + x0.y*p0.y + x0.z*p0.z + x0.w*p0.w          \
                  + x1.x*p1.x + x1.y*p1.y + x1.z*p1.z + x1.w*p1.w;         \
        _Pragma("unroll")                                                   \
        for (int o_ = 32; o_ >= 1; o_ >>= 1) dot += __shfl_xor(dot, o_);    \
        if (l == 0) r_lds[i_] = dot;                                        \
        const float pi_ = p_lds[i_];                                        \
        c0.x += pi_*x0.x; c0.y += pi_*x0.y; c0.z += pi_*x0.z; c0.w += pi_*x0.w; \
        c1.x += pi_*x1.x; c1.y += pi_*x1.y; c1.z += pi_*x1.z; c1.w += pi_*x1.w; \
    } } while (0)

    COMP1(A, 0); LOADG(A, 2);
    COMP1(B, 1); LOADG(B, 3);
    COMP1(A, 2); LOADG(A, 4);
    COMP1(B, 3); LOADG(B, 5);
    COMP1(A, 4); LOADG(A, 6);
    COMP1(B, 5); LOADG(B, 7);
    COMP1(A, 6);
    COMP1(B, 7);

    // ---------------- Mid: reduce c-partials, compute s ------------------
    *(float4*)&cst[w][4 * l] = c0;
    *(float4*)&cst[w][256 + 4 * l] = c1;
    // Prefetch phase-2's first two groups across the reduction barriers.
    LOADG(A, 7);
    LOADG(B, 6);
    __syncthreads();
    if (t < FDIM) {
        float cc = 0.f;
        #pragma unroll
        for (int j = 0; j < 16; ++j) cc += cst[j][t];
        c_lds[t] = cc;
    }
    float sv = (t < FDIM) ? p_lds[t] * r_lds[t] : 0.f;
    #pragma unroll
    for (int off = 32; off >= 1; off >>= 1) sv += __shfl_xor(sv, off);
    if (l == 0) red[w] = sv;
    __syncthreads();
    if (t == 0) {
        float tt = 0.f;
        for (int j = 0; j < 16; ++j) tt += red[j];
        sc[1] = tt;
    }
    __syncthreads();
    const float s = sc[1];
    const float4 cc0 = ld4(&c_lds[4 * l]);
    const float4 cc1 = ld4(&c_lds[256 + 4 * l]);

    // ---------------- Phase 2: out = p_i p_k (Sigma + (s-r_i) - c_k) ----
    // Reverse group order (rows just read are re-read first -> L2/L3 hot).
#define COMP2(arr, g) do {                                                  \
    _Pragma("unroll")                                                       \
    for (int q_ = 0; q_ < 4; ++q_) {                                        \
        const int i_ = i0 + (g) * 4 + q_;                                   \
        const float4 x0 = arr[2*q_], x1 = arr[2*q_+1];                      \
        const float pi_ = p_lds[i_];                                        \
        const float f_ = s - r_lds[i_];                                     \
        float4 o0, o1;                                                      \
        o0.x = pi_*p0.x*(x0.x + (f_ - cc0.x));                              \
        o0.y = pi_*p0.y*(x0.y + (f_ - cc0.y));                              \
        o0.z = pi_*p0.z*(x0.z + (f_ - cc0.z));                              \
        o0.w = pi_*p0.w*(x0.w + (f_ - cc0.w));                              \
        o1.x = pi_*p1.x*(x1.x + (f_ - cc1.x));                              \
        o1.y = pi_*p1.y*(x1.y + (f_ - cc1.y));                              \
        o1.z = pi_*p1.z*(x1.z + (f_ - cc1.z));                              \
        o1.w = pi_*p1.w*(x1.w + (f_ - cc1.w));                              \
        float* op_ = Ob + (size_t)i_ * FDIM + 4 * l;                        \
        *(float4*)op_ = o0;                                                 \
        *(float4*)(op_ + 256) = o1;                                         \
    } } while (0)

    COMP2(A, 7); LOADG(A, 5);
    COMP2(B, 6); LOADG(B, 4);
    COMP2(A, 5); LOADG(A, 3);
    COMP2(B, 4); LOADG(B, 2);
    COMP2(A, 3); LOADG(A, 1);
    COMP2(B, 2); LOADG(B, 0);
    COMP2(A, 1);
    COMP2(B, 0);

#undef LOADG
#undef COMP1
#undef COMP2
}

extern "C" void kernel_launch(void* const* d_in, const int* in_sizes, int n_in,
                              void* d_out, int out_size, void* d_ws, size_t ws_size,
                              hipStream_t stream) {
    (void)in_sizes; (void)n_in; (void)out_size; (void)d_ws; (void)ws_size;
    const float* mu    = (const float*)d_in[0];
    const float* Sigma = (const float*)d_in[1];
    float* p_out = (float*)d_out;
    float* S_out = (float*)d_out + (size_t)256 * 512;
    hipLaunchKernelGGL(rvsoftmax_deep, dim3(256), dim3(1024), 0, stream,
                       mu, Sigma, p_out, S_out);
}